// Round 15
// baseline (139.089 us; speedup 1.0000x reference)
//
#include <hip/hip_runtime.h>
#include <hip/hip_fp16.h>
#include <stdint.h>

#define NCTX 5952
#define NHEAD 16
#define NABLK 372          // NCTX/16 16-row blocks
#define NWBLK 256          // 4096/16

typedef _Float16 f16x8 __attribute__((ext_vector_type(8)));
typedef _Float16 f16x4 __attribute__((ext_vector_type(4)));
typedef float    f32x4 __attribute__((ext_vector_type(4)));

typedef const __attribute__((address_space(1))) void* gp1;
typedef __attribute__((address_space(3))) void* lp3;

__device__ __forceinline__ f32x4 mfma16(f16x8 a, f16x8 b, f32x4 c) {
    return __builtin_amdgcn_mfma_f32_16x16x32_f16(a, b, c, 0, 0, 0);
}

// attn still uses block-wide staging: fenced barrier (R12 lesson)
#define SBAR() do { __builtin_amdgcn_sched_barrier(0); \
                    __builtin_amdgcn_s_barrier();      \
                    __builtin_amdgcn_sched_barrier(0); } while (0)

// per-seq tables: lengths {512,576,640,704,768,832,896,1024}
__device__ const int kQT[9]    = {0, 4, 9, 14, 20, 26, 33, 40, 48};
__device__ const int kBASE8[8] = {0, 512, 1088, 1728, 2432, 3200, 4032, 4928};
__device__ const int kLEN[8]   = {512, 576, 640, 704, 768, 832, 896, 1024};

// ============================================================================
// Tiled staged layout (unchanged): array = [blk16][32 tsteps][1KB chunk],
// chunk = [16 rows][4 granule-slots][8 f16], granule g at slot g^((row>>1)&3).
// ============================================================================

// ---- fused pre-split: fp32 -> f16, tiled layout (unchanged) ----
__global__ __launch_bounds__(256) void presplit_all(
    const float* __restrict__ x,
    const float* __restrict__ Wq, const float* __restrict__ Wk,
    const float* __restrict__ Wv, const float* __restrict__ Wo,
    _Float16* __restrict__ Ah, _Float16* __restrict__ Wh)
{
    constexpr int NAG = NABLK * 32 * 64;
    const int idx = blockIdx.x * 256 + threadIdx.x;
    const float* src;
    _Float16* dst;
    if (idx < NAG) {
        int chunk = idx >> 6, within = idx & 63;
        int t = chunk & 31, b = chunk >> 5;
        int rb = within >> 2, go = within & 3;
        int r = b * 16 + rb;
        int g = go ^ ((r >> 1) & 3);
        src = x + (size_t)r * 1024 + t * 32 + g * 8;
        dst = Ah + (size_t)idx * 8;
    } else {
        int i2 = idx - NAG;
        int chunk = i2 >> 6, within = i2 & 63;
        int t = chunk & 31, b = chunk >> 5;
        int rb = within >> 2, go = within & 3;
        int n = b * 16 + rb;
        int g = go ^ ((n >> 1) & 3);
        const float* s = (n < 1024) ? Wq : (n < 2048) ? Wk : (n < 3072) ? Wv : Wo;
        src = s + (size_t)(n & 1023) * 1024 + t * 32 + g * 8;
        dst = Wh + (size_t)i2 * 8;
    }
    f32x4 v0 = *(const f32x4*)src;
    f32x4 v1 = *(const f32x4*)(src + 4);
    f16x8 hv;
    #pragma unroll
    for (int e = 0; e < 4; ++e) { hv[e] = (_Float16)v0[e]; hv[4 + e] = (_Float16)v1[e]; }
    *(f16x8*)dst = hv;
}

// ---- wave-private barrier-free GEMM: C = A*B^T, K=1024, BK=32, T=32 ----
// Each wave owns a 96xWN output tile and its OWN 3-buffer LDS staging region:
// ZERO s_barrier in the K-loop; self-paced counted vmcnt (never 0 mid-loop);
// register ping-pong preloads tile t+1's frags under tile t's MFMA cluster.
// Correctness is wave-local: reads of a buffer are consumed by MFMAs that
// issue before the next STG to that buffer (in-order issue + compiler lgkm).
// MODE 0: block 192x192 (2x2 waves of 96x96), grid 31x16=496, q/k/v epilogue
// MODE 1: block 192x128 (2x2 waves of 96x64), grid 31x8 =248, fp32 out + bo
template <int MODE>
__global__ __launch_bounds__(256, 1) void gemmwp(
    const _Float16* __restrict__ Ag, const _Float16* __restrict__ Wg,
    const float* __restrict__ bq, const float* __restrict__ bv, const float* __restrict__ bo,
    _Float16* __restrict__ qh, _Float16* __restrict__ kh, _Float16* __restrict__ vt,
    float* __restrict__ outp)
{
    constexpr int BN   = (MODE == 0) ? 192 : 128;
    constexpr int WN   = BN / 2;            // 96 / 64 cols per wave
    constexpr int NJ   = WN / 16;           // 6 / 4 col-frags
    constexpr int ACH  = 6, BCH = NJ;       // 1KB chunks per step per wave
    constexpr int AB   = ACH * 1024;
    constexpr int WBUF = AB + BCH * 1024;   // 12288 / 10240
    constexpr int T    = 32;
    constexpr int WB0  = (MODE == 0) ? 0 : 192;
    constexpr int NT   = (MODE == 0) ? 16 : 8;
    constexpr int CPX  = (31 * NT) / 8;     // 62 / 31

    __shared__ __align__(16) char lds[4 * 3 * WBUF];   // 144KB / 120KB

    int bid = blockIdx.x;
    bid = (bid & 7) * CPX + (bid >> 3);     // bijective XCD swizzle
    const int mt = bid % 31, nt = bid / 31; // XCD owns contiguous nt range
    const int tid = threadIdx.x;
    const int w = tid >> 6, l = tid & 63;
    const int ls = l >> 4, lq = l & 15;
    const int wm = w >> 1, wn = w & 1;
    const int m0 = mt * 192 + wm * 96;
    const int n0 = nt * BN + wn * WN;

    // per-wave DMA sources (1KB linear chunks from the tiled arrays)
    const char* asrc[ACH]; const char* bsrc[BCH];
    #pragma unroll
    for (int f = 0; f < ACH; ++f)
        asrc[f] = (const char*)Ag + (size_t)(m0 / 16 + f) * 32768 + l * 16;
    #pragma unroll
    for (int f = 0; f < BCH; ++f)
        bsrc[f] = (const char*)Wg + (size_t)(WB0 + n0 / 16 + f) * 32768 + l * 16;
    char* const wlds = lds + (size_t)w * (3 * WBUF);

    auto STG = [&](int buf, int t2) {
        char* d = wlds + buf * WBUF;
        #pragma unroll
        for (int f = 0; f < ACH; ++f)
            __builtin_amdgcn_global_load_lds((gp1)(asrc[f] + (size_t)t2 * 1024),
                                             (lp3)(d + f * 1024), 16, 0, 0);
        #pragma unroll
        for (int f = 0; f < BCH; ++f)
            __builtin_amdgcn_global_load_lds((gp1)(bsrc[f] + (size_t)t2 * 1024),
                                             (lp3)(d + AB + f * 1024), 16, 0, 0);
    };
    // counted waits; N = chunks per tile per wave (12 / 10)
    #define VMN() do { if constexpr (MODE == 0) asm volatile("s_waitcnt vmcnt(12)" ::: "memory"); \
                       else                     asm volatile("s_waitcnt vmcnt(10)" ::: "memory"); } while (0)
    #define VM0() asm volatile("s_waitcnt vmcnt(0)" ::: "memory")

    // fragment offsets within a wave buffer (proven 0-conflict swizzle)
    const int swz = (ls ^ ((lq >> 1) & 3)) << 4;
    int aoA[6], aoB[NJ];
    #pragma unroll
    for (int i = 0; i < 6; ++i) aoA[i] = i * 1024 + lq * 64 + swz;
    #pragma unroll
    for (int j = 0; j < NJ; ++j) aoB[j] = AB + j * 1024 + lq * 64 + swz;

    f32x4 acc[6][NJ] = {};
    f16x8 a0[6], b0[NJ], a1[6], b1[NJ];

    // prologue: stage tiles 0,1; wait tile0 (tile1 stays in flight); read frags0
    STG(0, 0);
    STG(1, 1);
    VMN();
    #pragma unroll
    for (int i = 0; i < 6; ++i) a0[i] = *(const f16x8*)(wlds + aoA[i]);
    #pragma unroll
    for (int j = 0; j < NJ; ++j) b0[j] = *(const f16x8*)(wlds + aoB[j]);

    int c = 0, n = 1, p = 2;
    #pragma unroll 1
    for (int t = 0; t < T; t += 2) {
        // ---- even: stage t+2 -> p; gate t+1; preload frags(t+1); MFMA(t) ----
        if (t + 2 < T) { STG(p, t + 2); VMN(); }
        else           { VM0(); }
        {
            const char* pn = wlds + n * WBUF;
            #pragma unroll
            for (int i = 0; i < 6; ++i) a1[i] = *(const f16x8*)(pn + aoA[i]);
            #pragma unroll
            for (int j = 0; j < NJ; ++j) b1[j] = *(const f16x8*)(pn + aoB[j]);
        }
        #pragma unroll
        for (int i = 0; i < 6; ++i)
            #pragma unroll
            for (int j = 0; j < NJ; ++j)
                acc[i][j] = mfma16(a0[i], b0[j], acc[i][j]);

        // ---- odd: stage t+3 -> c; gate t+2; preload frags(t+2); MFMA(t+1) ----
        if (t + 3 < T)      { STG(c, t + 3); VMN(); }
        else if (t + 2 < T) { VM0(); }
        if (t + 2 < T) {
            const char* pp = wlds + p * WBUF;
            #pragma unroll
            for (int i = 0; i < 6; ++i) a0[i] = *(const f16x8*)(pp + aoA[i]);
            #pragma unroll
            for (int j = 0; j < NJ; ++j) b0[j] = *(const f16x8*)(pp + aoB[j]);
        }
        #pragma unroll
        for (int i = 0; i < 6; ++i)
            #pragma unroll
            for (int j = 0; j < NJ; ++j)
                acc[i][j] = mfma16(a1[i], b1[j], acc[i][j]);

        // rotate buffers: next pair's (c,n,p) = (p,c,n)
        int oc = c, on = n, op = p;
        c = op; n = oc; p = on;
    }
    #undef VMN
    #undef VM0

    // C/D layout: col = lane&15 (-> n), row = (lane>>4)*4 + reg (-> m)
    #pragma unroll
    for (int i = 0; i < 6; ++i)
        #pragma unroll
        for (int j = 0; j < NJ; ++j) {
            const int mb = m0 + i * 16 + 4 * ls;
            const int nn2 = n0 + j * 16 + lq;
            if (MODE == 0) {
                const int which = nn2 >> 10, nn = nn2 & 1023;
                const int hh = nn >> 6, dd = nn & 63;
                if (which == 2) {
                    f16x4 vv;
                    #pragma unroll
                    for (int r = 0; r < 4; ++r) vv[r] = (_Float16)(acc[i][j][r] + bv[nn]);
                    *(f16x4*)&vt[((size_t)hh * 64 + dd) * NCTX + mb] = vv;   // d-major
                } else if (which == 0) {
                    #pragma unroll
                    for (int r = 0; r < 4; ++r)
                        qh[((size_t)hh * NCTX + mb + r) * 64 + dd] = (_Float16)(acc[i][j][r] + bq[nn]);
                } else {
                    #pragma unroll
                    for (int r = 0; r < 4; ++r)
                        kh[((size_t)hh * NCTX + mb + r) * 64 + dd] = (_Float16)acc[i][j][r];
                }
            } else {
                #pragma unroll
                for (int r = 0; r < 4; ++r)
                    outp[(size_t)(mb + r) * 1024 + nn2] = acc[i][j][r] + bo[nn2];
            }
        }
}

// ---- flash attention (no-max), 4 waves x 32 q-rows per 128-row tile ----
// (unchanged from R14: block-cooperative dbuf K/V staging, fenced barriers)
__global__ __launch_bounds__(256) void attn_kernel(
    const _Float16* __restrict__ qh, const _Float16* __restrict__ kh,
    const _Float16* __restrict__ vt,
    _Float16* __restrict__ Ahc)
{
    __shared__ alignas(16) _Float16 KT[2][64][64];
    __shared__ alignas(16) _Float16 VT[2][64][64];
    __shared__ alignas(16) _Float16 P[4][2][16][64];
    const int bid = blockIdx.x;
    const int hd = bid & 15, t = bid >> 4;
    int b = 0;
    while (t >= kQT[b + 1]) ++b;
    const int kbase = kBASE8[b];
    const int L = kLEN[b];
    const int w = threadIdx.x >> 6, l = threadIdx.x & 63;
    const int ls = l >> 4, lq = l & 15;
    const int xm = lq & 7;
    const int q0l = (t - kQT[b]) * 128 + w * 32;
    const bool active = (q0l < L);
    const int q0 = kbase + q0l;

    const _Float16* kb = kh + (size_t)hd * NCTX * 64;
    const _Float16* vb = vt + (size_t)hd * 64 * NCTX;

    const char* ksrc[2]; const char* vsrc[2]; int sdst[2];
    #pragma unroll
    for (int s = 0; s < 2; ++s) {
        int G = w * 128 + s * 64 + l;
        int row = G >> 3, g = G & 7;
        ksrc[s] = (const char*)(kb + ((size_t)(kbase + row)) * 64 + (size_t)((g ^ (row & 7)) * 8));
        vsrc[s] = (const char*)(vb + (size_t)row * NCTX + kbase + (size_t)((g ^ (row & 7)) * 8));
        sdst[s] = (w * 128 + s * 64) * 16;
    }
    auto STG = [&](int buf, int t2) {
        #pragma unroll
        for (int s = 0; s < 2; ++s)
            __builtin_amdgcn_global_load_lds((gp1)(ksrc[s] + (size_t)t2 * 8192),
                                             (lp3)((char*)&KT[buf][0][0] + sdst[s]), 16, 0, 0);
        #pragma unroll
        for (int s = 0; s < 2; ++s)
            __builtin_amdgcn_global_load_lds((gp1)(vsrc[s] + (size_t)t2 * 128),
                                             (lp3)((char*)&VT[buf][0][0] + sdst[s]), 16, 0, 0);
    };

    f16x8 qf[2][2];
    if (active) {
        #pragma unroll
        for (int qg = 0; qg < 2; ++qg) {
            const _Float16* qp = qh + ((size_t)hd * NCTX + q0 + qg * 16 + lq) * 64 + ls * 8;
            qf[qg][0] = *(const f16x8*)qp;
            qf[qg][1] = *(const f16x8*)(qp + 32);
        }
    }

    f32x4 acc[2][4] = {};
    float lsum[2] = {0.f, 0.f};
    const int nst = L >> 6;

    STG(0, 0);
    #pragma unroll 1
    for (int tt = 0; tt < nst; ++tt) {
        const int buf = tt & 1;
        if (tt + 1 < nst) {
            STG(buf ^ 1, tt + 1);
            asm volatile("s_waitcnt vmcnt(4)" ::: "memory");
        } else {
            asm volatile("s_waitcnt vmcnt(0)" ::: "memory");
        }
        SBAR();

        if (active) {
            f32x4 s[2][4];
            __builtin_amdgcn_s_setprio(1);
            #pragma unroll
            for (int g = 0; g < 4; ++g) {
                const char* kp = (const char*)&KT[buf][g * 16 + lq][0];
                f16x8 kf0 = *(const f16x8*)(kp + ((ls ^ xm) * 16));
                f16x8 kf1 = *(const f16x8*)(kp + (((ls + 4) ^ xm) * 16));
                #pragma unroll
                for (int qg = 0; qg < 2; ++qg) {
                    f32x4 z = {};
                    z = mfma16(kf0, qf[qg][0], z);
                    z = mfma16(kf1, qf[qg][1], z);
                    s[qg][g] = z;
                }
            }
            __builtin_amdgcn_s_setprio(0);
            #pragma unroll
            for (int qg = 0; qg < 2; ++qg) {
                float tsum = 0.f;
                #pragma unroll
                for (int g = 0; g < 4; ++g) {
                    f16x4 ph;
                    #pragma unroll
                    for (int r = 0; r < 4; ++r) {
                        float pv = __expf(s[qg][g][r] * 0.125f);
                        tsum += pv;
                        ph[r] = (_Float16)pv;
                    }
                    int gi = 2 * g + (ls >> 1);
                    *(f16x4*)&P[w][qg][lq][(((gi ^ (lq & 7)) << 3) | ((ls & 1) << 2))] = ph;
                }
                tsum += __shfl_xor(tsum, 16, 64);
                tsum += __shfl_xor(tsum, 32, 64);
                lsum[qg] += tsum;
            }
            __builtin_amdgcn_s_setprio(1);
            #pragma unroll
            for (int c = 0; c < 2; ++c) {
                f16x8 pf[2];
                #pragma unroll
                for (int qg = 0; qg < 2; ++qg)
                    pf[qg] = *(const f16x8*)&P[w][qg][lq][((4 * c + ls) ^ (lq & 7)) << 3];
                #pragma unroll
                for (int dg = 0; dg < 4; ++dg) {
                    const char* vp = (const char*)&VT[buf][dg * 16 + lq][0];
                    f16x8 vf = *(const f16x8*)(vp + (((c * 4 + ls) ^ xm) * 16));
                    #pragma unroll
                    for (int qg = 0; qg < 2; ++qg)
                        acc[qg][dg] = mfma16(vf, pf[qg], acc[qg][dg]);
                }
            }
            __builtin_amdgcn_s_setprio(0);
        }

        asm volatile("s_waitcnt lgkmcnt(0)" ::: "memory");
        SBAR();
    }

    if (active) {
        #pragma unroll
        for (int qg = 0; qg < 2; ++qg) {
            const float inv = 1.f / lsum[qg];
            const int m = q0 + qg * 16 + lq;
            const int bA = m >> 4, rbA = m & 15, xr = (m >> 1) & 3;
            #pragma unroll
            for (int dg = 0; dg < 4; ++dg) {
                const int k  = hd * 64 + dg * 16 + 4 * ls;
                const int tK = k >> 5;
                const int gs = ((k >> 3) & 3) ^ xr;
                const int e  = k & 7;
                f16x4 ch;
                #pragma unroll
                for (int r = 0; r < 4; ++r) ch[r] = (_Float16)(acc[qg][dg][r] * inv);
                *(f16x4*)((char*)Ahc + ((size_t)(bA * 32 + tK)) * 1024 + rbA * 64 + gs * 16 + e * 2) = ch;
            }
        }
    }
}

extern "C" void kernel_launch(void* const* d_in, const int* in_sizes, int n_in,
                              void* d_out, int out_size, void* d_ws, size_t ws_size,
                              hipStream_t stream)
{
    const float* x  = (const float*)d_in[0];
    const float* Wq = (const float*)d_in[1];
    const float* bq = (const float*)d_in[2];
    const float* Wk = (const float*)d_in[3];
    const float* Wv = (const float*)d_in[4];
    const float* bv = (const float*)d_in[5];
    const float* Wo = (const float*)d_in[6];
    const float* bo = (const float*)d_in[7];
    float* out = (float*)d_out;

    char* p = (char*)d_ws;
    _Float16* Ah  = (_Float16*)p; p += (size_t)NCTX * 1024 * 2;   // tiled
    _Float16* Wh  = (_Float16*)p; p += (size_t)4096 * 1024 * 2;   // tiled
    _Float16* qh  = (_Float16*)p; p += (size_t)NHEAD * NCTX * 64 * 2;
    _Float16* kh  = (_Float16*)p; p += (size_t)NHEAD * NCTX * 64 * 2;
    _Float16* vt  = (_Float16*)p; p += (size_t)NHEAD * NCTX * 64 * 2;
    _Float16* Ahc = (_Float16*)p; p += (size_t)NCTX * 1024 * 2;   // tiled

    presplit_all<<<dim3((NABLK * 32 * 64 + NWBLK * 32 * 64) / 256), 256, 0, stream>>>(
        x, Wq, Wk, Wv, Wo, Ah, Wh);
    gemmwp<0><<<dim3(31 * 16), 256, 0, stream>>>(Ah, Wh, bq, bv, nullptr,
                                                 qh, kh, vt, nullptr);
    attn_kernel<<<dim3(48 * 16), 256, 0, stream>>>(qh, kh, vt, Ahc);
    gemmwp<1><<<dim3(31 * 8), 256, 0, stream>>>(Ahc, Wh, nullptr, nullptr, bo,
                                                nullptr, nullptr, nullptr, out);
}